// Round 7
// baseline (214.366 us; speedup 1.0000x reference)
//
#include <hip/hip_runtime.h>
#include <stdint.h>

// EdgeAwareMultiHeadAttention on MI355X (gfx950) — round 7
// Changes vs round 6:
//  * adjacency PRE-TRANSPOSED (in prep, +256 blocks) to f16 quad-major layout
//    at[b][i>>4][j>>2][i&15][j&3]: flash's adjacency read becomes a fully
//    coalesced 512B uint2 load per instr. Rounds 1-6 all did a 16-cache-line
//    gather per adjacency instr (i varies across lanes, 8KB row stride) —
//    the one access pattern never fixed while everything else plateaued.
//  * flash: raw uint2 adjacency prefetch (full iter ahead), f16->f32 cvt at
//    use. Rest identical to r6 (glds dbuf K/V, S^T, P b64, MT template).

#define SEQ 2048
#define EMB 512
#define NH  8
#define HD  64
#define NB  2
#define L2E 1.4426950408889634f

typedef unsigned int   u32;
typedef unsigned short u16;
typedef u32   u32x4  __attribute__((ext_vector_type(4)));
typedef float f32x4  __attribute__((ext_vector_type(4)));
typedef __bf16 bf16x8 __attribute__((ext_vector_type(8)));
typedef _Float16 f16x4 __attribute__((ext_vector_type(4)));

#define MFMA16(a, b, c) __builtin_amdgcn_mfma_f32_16x16x32_bf16((a), (b), (c), 0, 0, 0)

static __device__ __forceinline__ u16 f2bf(float f) {
  return __builtin_bit_cast(u16, (__bf16)f);
}
static __device__ __forceinline__ u32 pack2(float a, float b) {
  return (u32)f2bf(a) | ((u32)f2bf(b) << 16);
}
static __device__ __forceinline__ u16 f2h(float f) {
  return __builtin_bit_cast(u16, (_Float16)f);
}
static __device__ __forceinline__ bf16x8 ldfrag(const u16* p) {
  return __builtin_bit_cast(bf16x8, *(const u32x4*)p);
}
static __device__ __forceinline__ void glds16(const u16* g, u16* l) {
  __builtin_amdgcn_global_load_lds(
      (const __attribute__((address_space(1))) u32*)(const void*)g,
      (__attribute__((address_space(3))) u32*)(void*)l, 16, 0, 0);
}

// Fragment-major K/V layouts, per (b,h) plane of 131072 u16 (2048x64):
//  ksw: (n,d) -> (n>>4)*1024 + (d>>5)*512 + (((d>>3)&3)*16 + (n&15))*8 + (d&7)
//  vsw: (n,d) -> (n>>6)*4096 + (d>>4)*1024 + ((n>>5)&1)*512
//               + (((n>>3)&3)*16 + (d&15))*8 + (n&7)
// Adjacency quad-major f16, per b plane of 4194304 u16:
//  at:  (i,j) -> (i>>4)*32768 + (j>>2)*64 + (i&15)*4 + (j&3)

// ---------------------------------------------------------------- prep
__global__ void prep_kernel(const float* __restrict__ x, const float* __restrict__ adj,
                            const float* __restrict__ Wq, const float* __restrict__ Wk,
                            const float* __restrict__ Wv, const float* __restrict__ Wo,
                            const float* __restrict__ We1, const float* __restrict__ be1,
                            const float* __restrict__ We2, const float* __restrict__ be2,
                            const float* __restrict__ ebias,
                            u16* __restrict__ xb, u16* __restrict__ wqkv,
                            u16* __restrict__ wob, float* __restrict__ co,
                            u16* __restrict__ at) {
  __shared__ float Ts[16 * 72];
  const int blk = blockIdx.x, tid = threadIdx.x;
  if (blk < 2048) {
    int i = (blk * 256 + tid) * 4;
    float4 v = *(const float4*)(x + i);
    *(uint2*)(xb + i) = make_uint2(pack2(v.x, v.y), pack2(v.z, v.w));
  } else if (blk < 3072) {
    int i = ((blk - 2048) * 256 + tid) * 4;
    int m = i >> 18;
    int off = i & 262143;
    const float* src = (m == 0) ? Wq : ((m == 1) ? Wk : ((m == 2) ? Wv : Wo));
    u16* dst = (m < 3) ? (wqkv + (size_t)m * 262144) : wob;
    float4 v = *(const float4*)(src + off);
    *(uint2*)(dst + off) = make_uint2(pack2(v.x, v.y), pack2(v.z, v.w));
  } else if (blk == 3072) {
    const int e = tid & 15, h = tid >> 4;
    if (tid < 128) {
      co[49 + e * 8 + h] = 0.0f;
      if (h == 0) { co[17 + e] = 0.0f; co[33 + e] = 0.0f; }
    }
    __syncthreads();
    if (tid < 128) {
      float w1 = We1[e], b1 = be1[e], w2 = We2[h * 16 + e];
      float u0 = b1, u1 = w1 + b1;
      bool on  = (u0 >= 0.0f) && (u1 >= 0.0f);
      bool off = (u0 <= 0.0f) && (u1 <= 0.0f);
      bool crossing = (!on) && (!off);
      float ca = on ? (w2 * b1) : (crossing ? 0.5f * w2 * b1 : 0.0f);
      float cb = on ? (w2 * w1) : (crossing ? 0.5f * w2 * w1 : 0.0f);
      #pragma unroll
      for (int d = 1; d < 16; d <<= 1) { ca += __shfl_xor(ca, d); cb += __shfl_xor(cb, d); }
      if (e == 0) { co[h] = (be2[h] + ca) * L2E; co[8 + h] = (ebias[h] + cb) * L2E; }
      unsigned long long msk = __ballot(crossing);
      int midx = __popcll(msk & 0xFFFFull & ((1ull << e) - 1ull));
      int mcnt = __popcll(msk & 0xFFFFull);
      if (crossing) {
        co[49 + midx * 8 + h] = 0.5f * w2 * L2E;
        if (h == 0) { co[17 + midx] = w1; co[33 + midx] = b1; }
      }
      if (tid == 0) ((int*)co)[16] = mcnt;
    }
  } else {
    // adjacency transpose: block = (b, i-tile of 16 rows)
    const int blk2 = blk - 3073;                 // 0..255
    const int b = blk2 >> 7, it16 = blk2 & 127;
    const float* src = adj + ((size_t)b * SEQ + it16 * 16) * SEQ;
    u16* dst = at + (size_t)b * 4194304 + (size_t)it16 * 32768;
    const int row = tid >> 4, jl = tid & 15;     // read mapping
    const int jq = tid >> 4, il = tid & 15;      // write mapping
    for (int jc = 0; jc < SEQ; jc += 64) {
      float4 v = *(const float4*)(src + (size_t)row * SEQ + jc + jl * 4);
      __syncthreads();
      *(float4*)&Ts[row * 72 + jl * 4] = v;
      __syncthreads();
      float a0 = Ts[il * 72 + jq * 4 + 0];
      float a1 = Ts[il * 72 + jq * 4 + 1];
      float a2 = Ts[il * 72 + jq * 4 + 2];
      float a3 = Ts[il * 72 + jq * 4 + 3];
      uint2 w2v = make_uint2((u32)f2h(a0) | ((u32)f2h(a1) << 16),
                             (u32)f2h(a2) | ((u32)f2h(a3) << 16));
      *(uint2*)(dst + (((jc >> 2) + jq) << 6) + il * 4) = w2v;
    }
  }
}

// ---------------------------------------------------------------- k1: QKV GEMM 64x128
#define LDA 40
__global__ __launch_bounds__(256) void gemm_qkv_kernel(
    const u16* __restrict__ A, const u16* __restrict__ Bm,
    const float* __restrict__ bq, const float* __restrict__ bk, const float* __restrict__ bv,
    u16* __restrict__ qh, u16* __restrict__ ksw, u16* __restrict__ vsw)
{
  __shared__ u16 sm[64 * LDA + 128 * LDA];   // As | Bs, reused by epilogue
  u16* As = sm;
  u16* Bs = sm + 64 * LDA;
  const int tid = threadIdx.x;
  const int lane = tid & 63, w = tid >> 6;
  const int q = lane >> 4, l15 = lane & 15;
  const int m0 = blockIdx.y * 64;
  const int n0 = blockIdx.x * 128;

  f32x4 acc[4][2];
  f32x4 zero = {0.f, 0.f, 0.f, 0.f};
  #pragma unroll
  for (int i = 0; i < 4; i++) { acc[i][0] = zero; acc[i][1] = zero; }

  const bool isA = tid < 128;
  const int arow_ = tid >> 1, ahalf = tid & 1;
  const int brow = tid - 128;
  const u16* ga = A  + (size_t)(m0 + arow_) * EMB + ahalf * 16;
  const u16* gb = Bm + (size_t)(n0 + brow) * EMB;
  u16* la = &As[arow_ * LDA + ahalf * 16];
  u16* lb = &Bs[brow * LDA];

  u32x4 p0, p1, p2, p3;
  if (isA) {
    p0 = *(const u32x4*)(ga); p1 = *(const u32x4*)(ga + 8); ga += 32;
  } else {
    p0 = *(const u32x4*)(gb);      p1 = *(const u32x4*)(gb + 8);
    p2 = *(const u32x4*)(gb + 16); p3 = *(const u32x4*)(gb + 24); gb += 32;
  }

  for (int k0 = 0; k0 < EMB; k0 += 32) {
    __syncthreads();
    if (isA) { *(u32x4*)(la) = p0; *(u32x4*)(la + 8) = p1; }
    else {
      *(u32x4*)(lb)      = p0; *(u32x4*)(lb + 8)  = p1;
      *(u32x4*)(lb + 16) = p2; *(u32x4*)(lb + 24) = p3;
    }
    __syncthreads();
    if (k0 + 32 < EMB) {
      if (isA) { p0 = *(const u32x4*)(ga); p1 = *(const u32x4*)(ga + 8); ga += 32; }
      else {
        p0 = *(const u32x4*)(gb);      p1 = *(const u32x4*)(gb + 8);
        p2 = *(const u32x4*)(gb + 16); p3 = *(const u32x4*)(gb + 24); gb += 32;
      }
    }
    bf16x8 af[4], bfr[2];
    #pragma unroll
    for (int mi = 0; mi < 4; mi++)
      af[mi] = ldfrag(&As[(mi*16 + l15) * LDA + q*8]);
    #pragma unroll
    for (int ni = 0; ni < 2; ni++)
      bfr[ni] = ldfrag(&Bs[(w*32 + ni*16 + l15) * LDA + q*8]);
    #pragma unroll
    for (int mi = 0; mi < 4; mi++)
      #pragma unroll
      for (int ni = 0; ni < 2; ni++)
        acc[mi][ni] = MFMA16(af[mi], bfr[ni], acc[mi][ni]);
  }

  // -------- epilogue: LDS-staged, per-head coalesced stores --------
  const int mat = n0 >> 9;                // 0:Q 1:K 2:V
  const float* bias = (mat == 0) ? bq : ((mat == 1) ? bk : bv);
  const float mul = (mat == 0) ? 0.125f * L2E : 1.0f;
  const int b_ = m0 >> 11;
  const int nbase = m0 & 2047;

  #pragma unroll
  for (int p = 0; p < 2; p++) {           // one head per pass
    __syncthreads();
    if ((w >> 1) == p) {
      #pragma unroll
      for (int ni = 0; ni < 2; ni++) {
        const int dd = (w & 1) * 32 + ni * 16 + l15;
        const float bsv = bias[(n0 & 511) + (w * 32 + ni * 16 + l15)];
        #pragma unroll
        for (int mi = 0; mi < 4; mi++) {
          #pragma unroll
          for (int r = 0; r < 4; r++) {
            const int nr = mi * 16 + q * 4 + r;
            const float val = (acc[mi][ni][r] + bsv) * mul;
            int idx;
            if (mat == 0)      idx = nr * 64 + dd;
            else if (mat == 1) idx = (nr >> 4) * 1024 + ((dd >> 5) << 9)
                                   + ((((dd >> 3) & 3) * 16 + (nr & 15)) << 3) + (dd & 7);
            else               idx = ((dd >> 4) << 10) + (((nr >> 5) & 1) << 9)
                                   + ((((nr >> 3) & 3) * 16 + (dd & 15)) << 3) + (nr & 7);
            sm[idx] = f2bf(val);
          }
        }
      }
    }
    __syncthreads();
    const int hh = ((n0 & 511) >> 6) + p;
    u16* gdst;
    if (mat == 0)      gdst = qh  + ((size_t)(b_ * NH + hh) * SEQ + nbase) * HD;
    else if (mat == 1) gdst = ksw + (size_t)(b_ * NH + hh) * 131072 + (nbase >> 4) * 1024;
    else               gdst = vsw + (size_t)(b_ * NH + hh) * 131072 + (nbase >> 6) * 4096;
    *(u32x4*)(gdst + tid * 16)     = *(const u32x4*)(sm + tid * 16);
    *(u32x4*)(gdst + tid * 16 + 8) = *(const u32x4*)(sm + tid * 16 + 8);
  }
}

// ---------------------------------------------------------------- k3: out GEMM 64x64
__global__ __launch_bounds__(256) void gemm_out_kernel(
    const u16* __restrict__ A, const u16* __restrict__ Bm,
    const float* __restrict__ bo, float* __restrict__ out)
{
  __shared__ u16 As[64 * LDA];
  __shared__ u16 Bs[64 * LDA];
  const int tid = threadIdx.x;
  const int lane = tid & 63, w = tid >> 6;
  const int q = lane >> 4, l15 = lane & 15;
  const int m0 = blockIdx.y * 64;
  const int n0 = blockIdx.x * 64;

  f32x4 acc[4];
  f32x4 zero = {0.f, 0.f, 0.f, 0.f};
  #pragma unroll
  for (int i = 0; i < 4; i++) acc[i] = zero;

  const bool isA = tid < 128;
  const int row = isA ? (tid >> 1) : ((tid - 128) >> 1);
  const int half = tid & 1;
  const u16* g = (isA ? A + (size_t)(m0 + row) * EMB : Bm + (size_t)(n0 + row) * EMB)
               + half * 16;
  u16* l = (isA ? &As[row * LDA] : &Bs[row * LDA]) + half * 16;

  u32x4 p0 = *(const u32x4*)(g);
  u32x4 p1 = *(const u32x4*)(g + 8);
  g += 32;

  for (int k0 = 0; k0 < EMB; k0 += 32) {
    __syncthreads();
    *(u32x4*)(l) = p0; *(u32x4*)(l + 8) = p1;
    __syncthreads();
    if (k0 + 32 < EMB) {
      p0 = *(const u32x4*)(g); p1 = *(const u32x4*)(g + 8); g += 32;
    }
    bf16x8 af[4], bfr;
    #pragma unroll
    for (int mi = 0; mi < 4; mi++)
      af[mi] = ldfrag(&As[(mi*16 + l15) * LDA + q*8]);
    bfr = ldfrag(&Bs[(w*16 + l15) * LDA + q*8]);
    #pragma unroll
    for (int mi = 0; mi < 4; mi++)
      acc[mi] = MFMA16(af[mi], bfr, acc[mi]);
  }

  int col = n0 + w*16 + l15;
  float bsv = bo[col];
  #pragma unroll
  for (int mi = 0; mi < 4; mi++) {
    int rowb = m0 + mi*16 + q*4;
    #pragma unroll
    for (int r = 0; r < 4; r++)
      out[(size_t)(rowb + r) * EMB + col] = acc[mi][r] + bsv;
  }
}

// ---------------------------------------------------------------- k2: flash (glds dbuf)
template<int MT>
struct FlashCtx {
  const u16 *kgp, *vgp;        // (b,h) K/V plane bases
  const u16* aq;               // quad-major f16 adjacency base for this lane
  bf16x8 qf0, qf1;
  float Ah, Bh;
  float ctr[MT], dtr[MT], wtr[MT];
  int lane, w, q, l15;
};

template<int MT>
static __device__ __forceinline__ void flash_stage(const FlashCtx<MT>& c,
                                                   u16* Kb, u16* Vb, int it) {
  const int o = c.w * 1024 + c.lane * 8;
  const u16* kg = c.kgp + it * 4096;
  const u16* vg = c.vgp + it * 4096;
  glds16(kg + o,       Kb + o);
  glds16(kg + o + 512, Kb + o + 512);
  glds16(vg + o,       Vb + o);
  glds16(vg + o + 512, Vb + o + 512);
}

template<int MT>
static __device__ __forceinline__ void flash_iter(
    const FlashCtx<MT>& c, int it, u16* Kb, u16* Vb, u16* nKb, u16* nVb,
    u16* psw, uint2* avc, uint2* avn, f32x4* O, float& lsum)
{
  __syncthreads();                       // gates buf(it); drains glds issued last iter
  if (it + 1 < 32) flash_stage(c, nKb, nVb, it + 1);
  const int nx = (it + 1 < 32) ? it + 1 : 31;
  #pragma unroll
  for (int jt = 0; jt < 4; jt++)
    avn[jt] = *(const uint2*)(c.aq + ((nx * 16 + jt * 4) << 6));   // coalesced 512B
  __builtin_amdgcn_sched_barrier(0);     // keep prefetch above compute

  f32x4 zero = {0.f, 0.f, 0.f, 0.f};
  const int lo = c.lane * 8;

  // S^T = MFMA(kf, qf)
  f32x4 S[4];
  #pragma unroll
  for (int jt = 0; jt < 4; jt++) {
    bf16x8 kf0 = ldfrag(Kb + jt * 1024 + lo);
    bf16x8 kf1 = ldfrag(Kb + jt * 1024 + 512 + lo);
    f32x4 s = MFMA16(kf0, c.qf0, zero);
    S[jt] = MFMA16(kf1, c.qf1, s);
  }

  #pragma unroll
  for (int half = 0; half < 2; half++) {
    #pragma unroll
    for (int jj = 0; jj < 2; jj++) {
      const int jt = half * 2 + jj;
      f16x4 hv = __builtin_bit_cast(f16x4, avc[jt]);
      float p[4];
      #pragma unroll
      for (int r = 0; r < 4; r++) {
        float a = (float)hv[r];
        float e = fmaf(a, c.Bh, c.Ah);
        #pragma unroll
        for (int t = 0; t < MT; t++)
          e = fmaf(fabsf(fmaf(a, c.ctr[t], c.dtr[t])), c.wtr[t], e);
        p[r] = __builtin_amdgcn_exp2f(S[jt][r] + e);
        lsum += p[r];
      }
      *(uint2*)(psw + c.l15 * 72 + jt * 16 + c.q * 4) =
          make_uint2(pack2(p[0], p[1]), pack2(p[2], p[3]));
    }
    bf16x8 pf = ldfrag(psw + c.l15 * 72 + half * 32 + c.q * 8);
    #pragma unroll
    for (int dt = 0; dt < 4; dt++) {
      bf16x8 vf = ldfrag(Vb + dt * 1024 + half * 512 + lo);
      O[dt] = MFMA16(vf, pf, O[dt]);
    }
  }
}

template<int MT>
__device__ __forceinline__ void flash_body(
    u16* Kb0, u16* Kb1, u16* Vb0, u16* Vb1, u16* Pb,
    const u16* __restrict__ qh, const u16* __restrict__ ksw, const u16* __restrict__ vsw,
    const u16* __restrict__ at, const float* __restrict__ coeff, u16* __restrict__ om)
{
  const int tid = threadIdx.x, lane = tid & 63, w = tid >> 6;
  const int q = lane >> 4, l15 = lane & 15;
  const int i0 = blockIdx.x * 64;
  const int h = blockIdx.y, b = blockIdx.z;
  const int bh = b * NH + h;
  const int iw = i0 + w * 16;

  FlashCtx<MT> c;
  c.lane = lane; c.w = w; c.q = q; c.l15 = l15;
  c.Ah = coeff[h]; c.Bh = coeff[8 + h];
  #pragma unroll
  for (int t = 0; t < MT; t++) {
    c.ctr[t] = coeff[17 + t];
    c.dtr[t] = coeff[33 + t];
    c.wtr[t] = coeff[49 + t * 8 + h];
  }
  const u16* qrow = qh + ((size_t)bh * SEQ + iw + l15) * HD;
  c.qf0 = ldfrag(qrow + q * 8);
  c.qf1 = ldfrag(qrow + 32 + q * 8);
  c.kgp = ksw + (size_t)bh * 131072;
  c.vgp = vsw + (size_t)bh * 131072;
  c.aq  = at + (size_t)b * 4194304 + (size_t)(iw >> 4) * 32768 + q * 64 + l15 * 4;

  f32x4 O[4];
  f32x4 zero = {0.f, 0.f, 0.f, 0.f};
  #pragma unroll
  for (int dt = 0; dt < 4; dt++) O[dt] = zero;
  float lsum = 0.0f;

  u16* psw = Pb + w * 1152;

  // prologue: stage tile 0 + adjacency 0
  flash_stage(c, Kb0, Vb0, 0);
  uint2 avA[4], avB[4];
  #pragma unroll
  for (int jt = 0; jt < 4; jt++)
    avA[jt] = *(const uint2*)(c.aq + ((jt * 4) << 6));

  #pragma unroll 1
  for (int it2 = 0; it2 < 32; it2 += 2) {
    flash_iter(c, it2,     Kb0, Vb0, Kb1, Vb1, psw, avA, avB, O, lsum);
    flash_iter(c, it2 + 1, Kb1, Vb1, Kb0, Vb0, psw, avB, avA, O, lsum);
  }

  lsum += __shfl_xor(lsum, 16);
  lsum += __shfl_xor(lsum, 32);
  float rl = 1.0f / lsum;

  u16* orow = om + ((size_t)b * SEQ + iw + l15) * EMB + h * HD + q * 4;
  #pragma unroll
  for (int dt = 0; dt < 4; dt++) {
    float v0 = O[dt][0] * rl, v1 = O[dt][1] * rl;
    float v2 = O[dt][2] * rl, v3 = O[dt][3] * rl;
    *(uint2*)(orow + dt * 16) = make_uint2(pack2(v0, v1), pack2(v2, v3));
  }
}

__global__ __launch_bounds__(256, 3) void flash_kernel(
    const u16* __restrict__ qh, const u16* __restrict__ ksw, const u16* __restrict__ vsw,
    const u16* __restrict__ at, const float* __restrict__ coeff, u16* __restrict__ om)
{
  __shared__ __align__(16) u16 Kb[2][4096];
  __shared__ __align__(16) u16 Vb[2][4096];
  __shared__ __align__(16) u16 Pb[4608];
  const int mt = ((const int*)coeff)[16];
  if (mt <= 4)
    flash_body<4>(Kb[0], Kb[1], Vb[0], Vb[1], Pb, qh, ksw, vsw, at, coeff, om);
  else if (mt <= 8)
    flash_body<8>(Kb[0], Kb[1], Vb[0], Vb[1], Pb, qh, ksw, vsw, at, coeff, om);
  else
    flash_body<16>(Kb[0], Kb[1], Vb[0], Vb[1], Pb, qh, ksw, vsw, at, coeff, om);
}

// ---------------------------------------------------------------- launch
extern "C" void kernel_launch(void* const* d_in, const int* in_sizes, int n_in,
                              void* d_out, int out_size, void* d_ws, size_t ws_size,
                              hipStream_t stream) {
  const float* x     = (const float*)d_in[0];
  const float* adj   = (const float*)d_in[1];
  const float* Wq    = (const float*)d_in[2];
  const float* bq    = (const float*)d_in[3];
  const float* Wk    = (const float*)d_in[4];
  const float* bk    = (const float*)d_in[5];
  const float* Wv    = (const float*)d_in[6];
  const float* bv    = (const float*)d_in[7];
  const float* Wo    = (const float*)d_in[8];
  const float* bo    = (const float*)d_in[9];
  const float* We1   = (const float*)d_in[10];
  const float* be1   = (const float*)d_in[11];
  const float* We2   = (const float*)d_in[12];
  const float* be2   = (const float*)d_in[13];
  const float* ebias = (const float*)d_in[14];
  float* out = (float*)d_out;

  char* ws = (char*)d_ws;
  u16*   xb   = (u16*)(ws + 0);          //  4 MB  x bf16
  u16*   wqkv = (u16*)(ws + 4194304);    //  1.5MB Wq|Wk|Wv bf16
  u16*   wob  = (u16*)(ws + 5767168);    //  0.5MB Wo bf16
  u16*   qh   = (u16*)(ws + 6291456);    //  4 MB  (B,H,N,64) row-major
  u16*   ksw  = (u16*)(ws + 10485760);   //  4 MB  fragment-major K
  u16*   vsw  = (u16*)(ws + 14680064);   //  4 MB  fragment-major V
  u16*   om   = (u16*)(ws + 18874368);   //  4 MB  (B,N,512) bf16
  float* co   = (float*)(ws + 23068672); //  4 KB  edge coefficients
  u16*   at   = (u16*)(ws + 23072768);   // 16 MB  quad-major f16 adjacency
  if (ws_size < 39849984) return;

  prep_kernel<<<3329, 256, 0, stream>>>(x, adj, Wq, Wk, Wv, Wo, We1, be1, We2, be2,
                                        ebias, xb, wqkv, wob, co, at);
  gemm_qkv_kernel<<<dim3(12, 64), 256, 0, stream>>>(xb, wqkv, bq, bk, bv, qh, ksw, vsw);
  flash_kernel<<<dim3(32, NH, NB), 256, 0, stream>>>(qh, ksw, vsw, at, co, om);
  gemm_out_kernel<<<dim3(8, 64), 256, 0, stream>>>(om, wob, bo, out);
}

// Round 8
// 193.435 us; speedup vs baseline: 1.1082x; 1.1082x over previous
//
#include <hip/hip_runtime.h>
#include <stdint.h>

// EdgeAwareMultiHeadAttention on MI355X (gfx950) — round 8
// Changes vs round 7:
//  * prep adjacency transpose PARALLELIZED: 2048 blocks (was 256 with a
//    32-iteration 2-barrier serial loop -> +30us regression). Now one
//    barrier per block, coalesced read & write, HBM-bound.
//  * flash: DEPTH-2 SOFTWARE PIPELINE on S — S(t+1) MFMAs issued during
//    iteration t, overlapping the edge/exp VALU block and PV MFMAs of t.
//    K staged 2 tiles ahead, V 1 ahead (same LDS, same barriers). The
//    per-wave serial chain S->edge->P->PV was the remaining stall;
//    MFMA+VALU pipes co-schedule (m114) once they're independent.

#define SEQ 2048
#define EMB 512
#define NH  8
#define HD  64
#define NB  2
#define L2E 1.4426950408889634f

typedef unsigned int   u32;
typedef unsigned short u16;
typedef u32   u32x4  __attribute__((ext_vector_type(4)));
typedef float f32x4  __attribute__((ext_vector_type(4)));
typedef __bf16 bf16x8 __attribute__((ext_vector_type(8)));
typedef _Float16 f16x4 __attribute__((ext_vector_type(4)));

#define MFMA16(a, b, c) __builtin_amdgcn_mfma_f32_16x16x32_bf16((a), (b), (c), 0, 0, 0)

static __device__ __forceinline__ u16 f2bf(float f) {
  return __builtin_bit_cast(u16, (__bf16)f);
}
static __device__ __forceinline__ u32 pack2(float a, float b) {
  return (u32)f2bf(a) | ((u32)f2bf(b) << 16);
}
static __device__ __forceinline__ u16 f2h(float f) {
  return __builtin_bit_cast(u16, (_Float16)f);
}
static __device__ __forceinline__ bf16x8 ldfrag(const u16* p) {
  return __builtin_bit_cast(bf16x8, *(const u32x4*)p);
}
static __device__ __forceinline__ void glds16(const u16* g, u16* l) {
  __builtin_amdgcn_global_load_lds(
      (const __attribute__((address_space(1))) u32*)(const void*)g,
      (__attribute__((address_space(3))) u32*)(void*)l, 16, 0, 0);
}

// Fragment-major K/V layouts, per (b,h) plane of 131072 u16 (2048x64):
//  ksw: (n,d) -> (n>>4)*1024 + (d>>5)*512 + (((d>>3)&3)*16 + (n&15))*8 + (d&7)
//  vsw: (n,d) -> (n>>6)*4096 + (d>>4)*1024 + ((n>>5)&1)*512
//               + (((n>>3)&3)*16 + (d&15))*8 + (n&7)
// Adjacency quad-major f16, per b plane of 4194304 u16:
//  at:  (i,j) -> (i>>4)*32768 + (j>>2)*64 + (i&15)*4 + (j&3)

// ---------------------------------------------------------------- prep
__global__ void prep_kernel(const float* __restrict__ x, const float* __restrict__ adj,
                            const float* __restrict__ Wq, const float* __restrict__ Wk,
                            const float* __restrict__ Wv, const float* __restrict__ Wo,
                            const float* __restrict__ We1, const float* __restrict__ be1,
                            const float* __restrict__ We2, const float* __restrict__ be2,
                            const float* __restrict__ ebias,
                            u16* __restrict__ xb, u16* __restrict__ wqkv,
                            u16* __restrict__ wob, float* __restrict__ co,
                            u16* __restrict__ at) {
  __shared__ float Ts[16 * 257];
  const int blk = blockIdx.x, tid = threadIdx.x;
  if (blk < 2048) {
    int i = (blk * 256 + tid) * 4;
    float4 v = *(const float4*)(x + i);
    *(uint2*)(xb + i) = make_uint2(pack2(v.x, v.y), pack2(v.z, v.w));
  } else if (blk < 3072) {
    int i = ((blk - 2048) * 256 + tid) * 4;
    int m = i >> 18;
    int off = i & 262143;
    const float* src = (m == 0) ? Wq : ((m == 1) ? Wk : ((m == 2) ? Wv : Wo));
    u16* dst = (m < 3) ? (wqkv + (size_t)m * 262144) : wob;
    float4 v = *(const float4*)(src + off);
    *(uint2*)(dst + off) = make_uint2(pack2(v.x, v.y), pack2(v.z, v.w));
  } else if (blk == 3072) {
    const int e = tid & 15, h = tid >> 4;
    if (tid < 128) {
      co[49 + e * 8 + h] = 0.0f;
      if (h == 0) { co[17 + e] = 0.0f; co[33 + e] = 0.0f; }
    }
    __syncthreads();
    if (tid < 128) {
      float w1 = We1[e], b1 = be1[e], w2 = We2[h * 16 + e];
      float u0 = b1, u1 = w1 + b1;
      bool on  = (u0 >= 0.0f) && (u1 >= 0.0f);
      bool off = (u0 <= 0.0f) && (u1 <= 0.0f);
      bool crossing = (!on) && (!off);
      float ca = on ? (w2 * b1) : (crossing ? 0.5f * w2 * b1 : 0.0f);
      float cb = on ? (w2 * w1) : (crossing ? 0.5f * w2 * w1 : 0.0f);
      #pragma unroll
      for (int d = 1; d < 16; d <<= 1) { ca += __shfl_xor(ca, d); cb += __shfl_xor(cb, d); }
      if (e == 0) { co[h] = (be2[h] + ca) * L2E; co[8 + h] = (ebias[h] + cb) * L2E; }
      unsigned long long msk = __ballot(crossing);
      int midx = __popcll(msk & 0xFFFFull & ((1ull << e) - 1ull));
      int mcnt = __popcll(msk & 0xFFFFull);
      if (crossing) {
        co[49 + midx * 8 + h] = 0.5f * w2 * L2E;
        if (h == 0) { co[17 + midx] = w1; co[33 + midx] = b1; }
      }
      if (tid == 0) ((int*)co)[16] = mcnt;
    }
  } else {
    // adjacency transpose: 2048 blocks = (b, i-tile of 16, j-chunk of 256)
    const int blk2 = blk - 3073;
    const int b = blk2 >> 10, rem = blk2 & 1023;
    const int it16 = rem >> 3, jc = (rem & 7) * 256;
    const float* src = adj + ((size_t)b * SEQ + it16 * 16) * SEQ + jc;
    u16* dst = at + (size_t)b * 4194304 + (size_t)it16 * 32768 + ((size_t)jc >> 2) * 64;
    const int row = tid >> 4, jl = tid & 15;
    #pragma unroll
    for (int p = 0; p < 4; p++) {
      float4 v = *(const float4*)(src + (size_t)row * SEQ + p * 64 + jl * 4);
      *(float4*)&Ts[row * 257 + p * 64 + jl * 4] = v;
    }
    __syncthreads();
    const int il = tid & 15;
    #pragma unroll
    for (int wv = 0; wv < 4; wv++) {
      const int jql = wv * 16 + (tid >> 4);
      float a0 = Ts[il * 257 + jql * 4 + 0];
      float a1 = Ts[il * 257 + jql * 4 + 1];
      float a2 = Ts[il * 257 + jql * 4 + 2];
      float a3 = Ts[il * 257 + jql * 4 + 3];
      *(uint2*)(dst + jql * 64 + il * 4) =
          make_uint2((u32)f2h(a0) | ((u32)f2h(a1) << 16),
                     (u32)f2h(a2) | ((u32)f2h(a3) << 16));
    }
  }
}

// ---------------------------------------------------------------- k1: QKV GEMM 64x128
#define LDA 40
__global__ __launch_bounds__(256) void gemm_qkv_kernel(
    const u16* __restrict__ A, const u16* __restrict__ Bm,
    const float* __restrict__ bq, const float* __restrict__ bk, const float* __restrict__ bv,
    u16* __restrict__ qh, u16* __restrict__ ksw, u16* __restrict__ vsw)
{
  __shared__ u16 sm[64 * LDA + 128 * LDA];
  u16* As = sm;
  u16* Bs = sm + 64 * LDA;
  const int tid = threadIdx.x;
  const int lane = tid & 63, w = tid >> 6;
  const int q = lane >> 4, l15 = lane & 15;
  const int m0 = blockIdx.y * 64;
  const int n0 = blockIdx.x * 128;

  f32x4 acc[4][2];
  f32x4 zero = {0.f, 0.f, 0.f, 0.f};
  #pragma unroll
  for (int i = 0; i < 4; i++) { acc[i][0] = zero; acc[i][1] = zero; }

  const bool isA = tid < 128;
  const int arow_ = tid >> 1, ahalf = tid & 1;
  const int brow = tid - 128;
  const u16* ga = A  + (size_t)(m0 + arow_) * EMB + ahalf * 16;
  const u16* gb = Bm + (size_t)(n0 + brow) * EMB;
  u16* la = &As[arow_ * LDA + ahalf * 16];
  u16* lb = &Bs[brow * LDA];

  u32x4 p0, p1, p2, p3;
  if (isA) {
    p0 = *(const u32x4*)(ga); p1 = *(const u32x4*)(ga + 8); ga += 32;
  } else {
    p0 = *(const u32x4*)(gb);      p1 = *(const u32x4*)(gb + 8);
    p2 = *(const u32x4*)(gb + 16); p3 = *(const u32x4*)(gb + 24); gb += 32;
  }

  for (int k0 = 0; k0 < EMB; k0 += 32) {
    __syncthreads();
    if (isA) { *(u32x4*)(la) = p0; *(u32x4*)(la + 8) = p1; }
    else {
      *(u32x4*)(lb)      = p0; *(u32x4*)(lb + 8)  = p1;
      *(u32x4*)(lb + 16) = p2; *(u32x4*)(lb + 24) = p3;
    }
    __syncthreads();
    if (k0 + 32 < EMB) {
      if (isA) { p0 = *(const u32x4*)(ga); p1 = *(const u32x4*)(ga + 8); ga += 32; }
      else {
        p0 = *(const u32x4*)(gb);      p1 = *(const u32x4*)(gb + 8);
        p2 = *(const u32x4*)(gb + 16); p3 = *(const u32x4*)(gb + 24); gb += 32;
      }
    }
    bf16x8 af[4], bfr[2];
    #pragma unroll
    for (int mi = 0; mi < 4; mi++)
      af[mi] = ldfrag(&As[(mi*16 + l15) * LDA + q*8]);
    #pragma unroll
    for (int ni = 0; ni < 2; ni++)
      bfr[ni] = ldfrag(&Bs[(w*32 + ni*16 + l15) * LDA + q*8]);
    #pragma unroll
    for (int mi = 0; mi < 4; mi++)
      #pragma unroll
      for (int ni = 0; ni < 2; ni++)
        acc[mi][ni] = MFMA16(af[mi], bfr[ni], acc[mi][ni]);
  }

  const int mat = n0 >> 9;
  const float* bias = (mat == 0) ? bq : ((mat == 1) ? bk : bv);
  const float mul = (mat == 0) ? 0.125f * L2E : 1.0f;
  const int b_ = m0 >> 11;
  const int nbase = m0 & 2047;

  #pragma unroll
  for (int p = 0; p < 2; p++) {
    __syncthreads();
    if ((w >> 1) == p) {
      #pragma unroll
      for (int ni = 0; ni < 2; ni++) {
        const int dd = (w & 1) * 32 + ni * 16 + l15;
        const float bsv = bias[(n0 & 511) + (w * 32 + ni * 16 + l15)];
        #pragma unroll
        for (int mi = 0; mi < 4; mi++) {
          #pragma unroll
          for (int r = 0; r < 4; r++) {
            const int nr = mi * 16 + q * 4 + r;
            const float val = (acc[mi][ni][r] + bsv) * mul;
            int idx;
            if (mat == 0)      idx = nr * 64 + dd;
            else if (mat == 1) idx = (nr >> 4) * 1024 + ((dd >> 5) << 9)
                                   + ((((dd >> 3) & 3) * 16 + (nr & 15)) << 3) + (dd & 7);
            else               idx = ((dd >> 4) << 10) + (((nr >> 5) & 1) << 9)
                                   + ((((nr >> 3) & 3) * 16 + (dd & 15)) << 3) + (nr & 7);
            sm[idx] = f2bf(val);
          }
        }
      }
    }
    __syncthreads();
    const int hh = ((n0 & 511) >> 6) + p;
    u16* gdst;
    if (mat == 0)      gdst = qh  + ((size_t)(b_ * NH + hh) * SEQ + nbase) * HD;
    else if (mat == 1) gdst = ksw + (size_t)(b_ * NH + hh) * 131072 + (nbase >> 4) * 1024;
    else               gdst = vsw + (size_t)(b_ * NH + hh) * 131072 + (nbase >> 6) * 4096;
    *(u32x4*)(gdst + tid * 16)     = *(const u32x4*)(sm + tid * 16);
    *(u32x4*)(gdst + tid * 16 + 8) = *(const u32x4*)(sm + tid * 16 + 8);
  }
}

// ---------------------------------------------------------------- k3: out GEMM 64x64
__global__ __launch_bounds__(256) void gemm_out_kernel(
    const u16* __restrict__ A, const u16* __restrict__ Bm,
    const float* __restrict__ bo, float* __restrict__ out)
{
  __shared__ u16 As[64 * LDA];
  __shared__ u16 Bs[64 * LDA];
  const int tid = threadIdx.x;
  const int lane = tid & 63, w = tid >> 6;
  const int q = lane >> 4, l15 = lane & 15;
  const int m0 = blockIdx.y * 64;
  const int n0 = blockIdx.x * 64;

  f32x4 acc[4];
  f32x4 zero = {0.f, 0.f, 0.f, 0.f};
  #pragma unroll
  for (int i = 0; i < 4; i++) acc[i] = zero;

  const bool isA = tid < 128;
  const int row = isA ? (tid >> 1) : ((tid - 128) >> 1);
  const int half = tid & 1;
  const u16* g = (isA ? A + (size_t)(m0 + row) * EMB : Bm + (size_t)(n0 + row) * EMB)
               + half * 16;
  u16* l = (isA ? &As[row * LDA] : &Bs[row * LDA]) + half * 16;

  u32x4 p0 = *(const u32x4*)(g);
  u32x4 p1 = *(const u32x4*)(g + 8);
  g += 32;

  for (int k0 = 0; k0 < EMB; k0 += 32) {
    __syncthreads();
    *(u32x4*)(l) = p0; *(u32x4*)(l + 8) = p1;
    __syncthreads();
    if (k0 + 32 < EMB) {
      p0 = *(const u32x4*)(g); p1 = *(const u32x4*)(g + 8); g += 32;
    }
    bf16x8 af[4], bfr;
    #pragma unroll
    for (int mi = 0; mi < 4; mi++)
      af[mi] = ldfrag(&As[(mi*16 + l15) * LDA + q*8]);
    bfr = ldfrag(&Bs[(w*16 + l15) * LDA + q*8]);
    #pragma unroll
    for (int mi = 0; mi < 4; mi++)
      acc[mi] = MFMA16(af[mi], bfr, acc[mi]);
  }

  int col = n0 + w*16 + l15;
  float bsv = bo[col];
  #pragma unroll
  for (int mi = 0; mi < 4; mi++) {
    int rowb = m0 + mi*16 + q*4;
    #pragma unroll
    for (int r = 0; r < 4; r++)
      out[(size_t)(rowb + r) * EMB + col] = acc[mi][r] + bsv;
  }
}

// ---------------------------------------------------------------- k2: flash (S-pipelined)
template<int MT>
struct FlashCtx {
  const u16 *kgp, *vgp;
  const u16* aq;
  bf16x8 qf0, qf1;
  float Ah, Bh;
  float ctr[MT], dtr[MT], wtr[MT];
  int lane, w, q, l15;
};

template<int MT>
static __device__ __forceinline__ void stageK(const FlashCtx<MT>& c, u16* Kb, int it) {
  const int o = c.w * 1024 + c.lane * 8;
  const u16* kg = c.kgp + it * 4096;
  glds16(kg + o,       Kb + o);
  glds16(kg + o + 512, Kb + o + 512);
}
template<int MT>
static __device__ __forceinline__ void stageV(const FlashCtx<MT>& c, u16* Vb, int it) {
  const int o = c.w * 1024 + c.lane * 8;
  const u16* vg = c.vgp + it * 4096;
  glds16(vg + o,       Vb + o);
  glds16(vg + o + 512, Vb + o + 512);
}

template<int MT>
static __device__ __forceinline__ void edge_exp_P(
    const FlashCtx<MT>& c, const f32x4* S, const uint2* avc, int jt,
    u16* psw, float& lsum)
{
  f16x4 hv = __builtin_bit_cast(f16x4, avc[jt]);
  float p[4];
  #pragma unroll
  for (int r = 0; r < 4; r++) {
    float a = (float)hv[r];
    float e = fmaf(a, c.Bh, c.Ah);
    #pragma unroll
    for (int t = 0; t < MT; t++)
      e = fmaf(fabsf(fmaf(a, c.ctr[t], c.dtr[t])), c.wtr[t], e);
    p[r] = __builtin_amdgcn_exp2f(S[jt][r] + e);
    lsum += p[r];
  }
  *(uint2*)(psw + c.l15 * 72 + jt * 16 + c.q * 4) =
      make_uint2(pack2(p[0], p[1]), pack2(p[2], p[3]));
}

// iter t: consumes S(t)=Scur (computed last iter) + avc(t); produces Snew=S(t+1).
// Kcur=Kb[t&1] (holds K(t), freed -> receives K(t+2)); Knext=Kb[(t+1)&1] (K(t+1)).
// Vcur=Vb[t&1] (V(t)); Vnext=Vb[(t+1)&1] (receives V(t+1)).
template<int MT>
static __device__ __forceinline__ void flash_iter(
    const FlashCtx<MT>& c, int t, u16* Kcur, u16* Knext, u16* Vcur, u16* Vnext,
    u16* psw, uint2* avc, uint2* avn, f32x4* Scur, f32x4* Snew, f32x4* O, float& lsum)
{
  __syncthreads();                       // all waves done with iter t-1; drains glds
  if (t + 2 < 32) stageK(c, Kcur, t + 2);
  if (t + 1 < 32) stageV(c, Vnext, t + 1);
  const int nx = (t + 1 < 32) ? t + 1 : 31;
  #pragma unroll
  for (int jt = 0; jt < 4; jt++)
    avn[jt] = *(const uint2*)(c.aq + ((nx * 16 + jt * 4) << 6));
  __builtin_amdgcn_sched_barrier(0);     // staging + prefetch stay above compute

  const int lo = c.lane * 8;
  f32x4 zero = {0.f, 0.f, 0.f, 0.f};

  // half0: edge/exp/P for jt 0,1 (VALU)
  edge_exp_P(c, Scur, avc, 0, psw, lsum);
  edge_exp_P(c, Scur, avc, 1, psw, lsum);

  // S(t+1) from Knext — independent of everything above; overlaps VALU + pf latency
  if (t < 31) {
    #pragma unroll
    for (int jt = 0; jt < 4; jt++) {
      bf16x8 kf0 = ldfrag(Knext + jt * 1024 + lo);
      bf16x8 kf1 = ldfrag(Knext + jt * 1024 + 512 + lo);
      f32x4 s = MFMA16(kf0, c.qf0, zero);
      Snew[jt] = MFMA16(kf1, c.qf1, s);
    }
  }

  // PV half0 (P write for jt0,1 precedes pf0 read in DS order)
  {
    bf16x8 pf0 = ldfrag(psw + c.l15 * 72 + c.q * 8);
    #pragma unroll
    for (int dt = 0; dt < 4; dt++) {
      bf16x8 vf = ldfrag(Vcur + dt * 1024 + lo);
      O[dt] = MFMA16(vf, pf0, O[dt]);
    }
  }

  // half1: edge/exp/P for jt 2,3 then PV half1
  edge_exp_P(c, Scur, avc, 2, psw, lsum);
  edge_exp_P(c, Scur, avc, 3, psw, lsum);
  {
    bf16x8 pf1 = ldfrag(psw + c.l15 * 72 + 32 + c.q * 8);
    #pragma unroll
    for (int dt = 0; dt < 4; dt++) {
      bf16x8 vf = ldfrag(Vcur + dt * 1024 + 512 + lo);
      O[dt] = MFMA16(vf, pf1, O[dt]);
    }
  }
}

template<int MT>
__device__ __forceinline__ void flash_body(
    u16* Kb0, u16* Kb1, u16* Vb0, u16* Vb1, u16* Pb,
    const u16* __restrict__ qh, const u16* __restrict__ ksw, const u16* __restrict__ vsw,
    const u16* __restrict__ at, const float* __restrict__ coeff, u16* __restrict__ om)
{
  const int tid = threadIdx.x, lane = tid & 63, w = tid >> 6;
  const int q = lane >> 4, l15 = lane & 15;
  const int i0 = blockIdx.x * 64;
  const int h = blockIdx.y, b = blockIdx.z;
  const int bh = b * NH + h;
  const int iw = i0 + w * 16;

  FlashCtx<MT> c;
  c.lane = lane; c.w = w; c.q = q; c.l15 = l15;
  c.Ah = coeff[h]; c.Bh = coeff[8 + h];
  #pragma unroll
  for (int t = 0; t < MT; t++) {
    c.ctr[t] = coeff[17 + t];
    c.dtr[t] = coeff[33 + t];
    c.wtr[t] = coeff[49 + t * 8 + h];
  }
  const u16* qrow = qh + ((size_t)bh * SEQ + iw + l15) * HD;
  c.qf0 = ldfrag(qrow + q * 8);
  c.qf1 = ldfrag(qrow + 32 + q * 8);
  c.kgp = ksw + (size_t)bh * 131072;
  c.vgp = vsw + (size_t)bh * 131072;
  c.aq  = at + (size_t)b * 4194304 + (size_t)(iw >> 4) * 32768 + q * 64 + l15 * 4;

  f32x4 O[4];
  f32x4 zero = {0.f, 0.f, 0.f, 0.f};
  #pragma unroll
  for (int dt = 0; dt < 4; dt++) O[dt] = zero;
  float lsum = 0.0f;

  u16* psw = Pb + w * 1152;

  // prologue: stage K(0),V(0),K(1); load av(0); compute S(0)
  stageK(c, Kb0, 0);
  stageV(c, Vb0, 0);
  stageK(c, Kb1, 1);
  uint2 avA[4], avB[4];
  #pragma unroll
  for (int jt = 0; jt < 4; jt++)
    avA[jt] = *(const uint2*)(c.aq + ((jt * 4) << 6));
  __syncthreads();                     // drains the three stages
  f32x4 SA[4], SB[4];
  {
    const int lo = lane * 8;
    #pragma unroll
    for (int jt = 0; jt < 4; jt++) {
      bf16x8 kf0 = ldfrag(Kb0 + jt * 1024 + lo);
      bf16x8 kf1 = ldfrag(Kb0 + jt * 1024 + 512 + lo);
      f32x4 s = MFMA16(kf0, c.qf0, zero);
      SA[jt] = MFMA16(kf1, c.qf1, s);
    }
  }

  #pragma unroll 1
  for (int t2 = 0; t2 < 32; t2 += 2) {
    flash_iter(c, t2,     Kb0, Kb1, Vb0, Vb1, psw, avA, avB, SA, SB, O, lsum);
    flash_iter(c, t2 + 1, Kb1, Kb0, Vb1, Vb0, psw, avB, avA, SB, SA, O, lsum);
  }

  lsum += __shfl_xor(lsum, 16);
  lsum += __shfl_xor(lsum, 32);
  float rl = 1.0f / lsum;

  u16* orow = om + ((size_t)b * SEQ + iw + l15) * EMB + h * HD + q * 4;
  #pragma unroll
  for (int dt = 0; dt < 4; dt++) {
    float v0 = O[dt][0] * rl, v1 = O[dt][1] * rl;
    float v2 = O[dt][2] * rl, v3 = O[dt][3] * rl;
    *(uint2*)(orow + dt * 16) = make_uint2(pack2(v0, v1), pack2(v2, v3));
  }
}

__global__ __launch_bounds__(256, 3) void flash_kernel(
    const u16* __restrict__ qh, const u16* __restrict__ ksw, const u16* __restrict__ vsw,
    const u16* __restrict__ at, const float* __restrict__ coeff, u16* __restrict__ om)
{
  __shared__ __align__(16) u16 Kb[2][4096];
  __shared__ __align__(16) u16 Vb[2][4096];
  __shared__ __align__(16) u16 Pb[4608];
  const int mt = ((const int*)coeff)[16];
  if (mt <= 4)
    flash_body<4>(Kb[0], Kb[1], Vb[0], Vb[1], Pb, qh, ksw, vsw, at, coeff, om);
  else if (mt <= 8)
    flash_body<8>(Kb[0], Kb[1], Vb[0], Vb[1], Pb, qh, ksw, vsw, at, coeff, om);
  else
    flash_body<16>(Kb[0], Kb[1], Vb[0], Vb[1], Pb, qh, ksw, vsw, at, coeff, om);
}

// ---------------------------------------------------------------- launch
extern "C" void kernel_launch(void* const* d_in, const int* in_sizes, int n_in,
                              void* d_out, int out_size, void* d_ws, size_t ws_size,
                              hipStream_t stream) {
  const float* x     = (const float*)d_in[0];
  const float* adj   = (const float*)d_in[1];
  const float* Wq    = (const float*)d_in[2];
  const float* bq    = (const float*)d_in[3];
  const float* Wk    = (const float*)d_in[4];
  const float* bk    = (const float*)d_in[5];
  const float* Wv    = (const float*)d_in[6];
  const float* bv    = (const float*)d_in[7];
  const float* Wo    = (const float*)d_in[8];
  const float* bo    = (const float*)d_in[9];
  const float* We1   = (const float*)d_in[10];
  const float* be1   = (const float*)d_in[11];
  const float* We2   = (const float*)d_in[12];
  const float* be2   = (const float*)d_in[13];
  const float* ebias = (const float*)d_in[14];
  float* out = (float*)d_out;

  char* ws = (char*)d_ws;
  u16*   xb   = (u16*)(ws + 0);          //  4 MB  x bf16
  u16*   wqkv = (u16*)(ws + 4194304);    //  1.5MB Wq|Wk|Wv bf16
  u16*   wob  = (u16*)(ws + 5767168);    //  0.5MB Wo bf16
  u16*   qh   = (u16*)(ws + 6291456);    //  4 MB  (B,H,N,64) row-major
  u16*   ksw  = (u16*)(ws + 10485760);   //  4 MB  fragment-major K
  u16*   vsw  = (u16*)(ws + 14680064);   //  4 MB  fragment-major V
  u16*   om   = (u16*)(ws + 18874368);   //  4 MB  (B,N,512) bf16
  float* co   = (float*)(ws + 23068672); //  4 KB  edge coefficients
  u16*   at   = (u16*)(ws + 23072768);   // 16 MB  quad-major f16 adjacency
  if (ws_size < 39849984) return;

  prep_kernel<<<5121, 256, 0, stream>>>(x, adj, Wq, Wk, Wv, Wo, We1, be1, We2, be2,
                                        ebias, xb, wqkv, wob, co, at);
  gemm_qkv_kernel<<<dim3(12, 64), 256, 0, stream>>>(xb, wqkv, bq, bk, bv, qh, ksw, vsw);
  flash_kernel<<<dim3(32, NH, NB), 256, 0, stream>>>(qh, ksw, vsw, at, co, om);
  gemm_out_kernel<<<dim3(8, 64), 256, 0, stream>>>(om, wob, bo, out);
}